// Round 12
// baseline (935.590 us; speedup 1.0000x reference)
//
#include <hip/hip_runtime.h>

#define NN 8192
#define SBS 512
#define NSB 16
#define LOG2E 1.44269504088896f

// ws floats (NO flags, NO atomics anywhere):
//   cp[8][NN]  at [0, 65536)   -- cross-block partial pre-activations, row = row-chunk
//   s_arr[NN]  at [65536, 73728)
#define CP_OFF   0
#define SARR_OFF (8 * NN)

__device__ __forceinline__ float bcastf(float v, int lane) {
    return __int_as_float(__builtin_amdgcn_readlane(__float_as_int(v), lane));
}
__device__ __forceinline__ float sigm(float prelog) {   // pre already in log2e units
    return __builtin_amdgcn_rcpf(1.0f + __builtin_amdgcn_exp2f(-prelog));
}
// barrier that does NOT drain vmcnt (keeps streamed prefetch loads in flight)
#define LBAR() do { asm volatile("s_waitcnt lgkmcnt(0)\ns_barrier" ::: "memory"); \
                    __builtin_amdgcn_sched_barrier(0); } while (0)

__global__ void init_ws(float* wsf) {
    int i = blockIdx.x * 256 + threadIdx.x;   // 256*256 = 65536 = 8*NN
    wsf[CP_OFF + i] = 0.0f;
}

// ---------- solver: 8 waves; wave w owns cols [k*512 + w*64, +64) ----------
// All intra-block folds done in-WG: at iteration m every wave folds its 8-row
// slice of source sub-block m into ALL future targets (register panels),
// accumulating in racc[]; red[t][*][*] is finalized at iteration t-1.
__device__ void solver_fn(const float* __restrict__ W, const float* __restrict__ b,
                          const float* __restrict__ x, float* wsf,
                          float* sdiag, float* spub, float (*red)[8][64],
                          float* __restrict__ out, int k) {
    const int tid = threadIdx.x;
    const int w = tid >> 6, l = tid & 63;
    const int dj = tid >> 3, dc = (tid & 7) * 8;   // diag staging role
    const int J0 = k * SBS;
    const float* cp = wsf + CP_OFF;
    float* s_arr = wsf + SARR_OFF;

    auto load_diag = [&](int mm, float4& a, float4& bq) {
        if (dj < dc + 7) {   // chunks entirely at/below diagonal are written as 0
            const float* p = &W[(size_t)(J0 + mm*64 + dj) * NN + (J0 + mm*64 + dc)];
            a  = *(const float4*)p;
            bq = *(const float4*)(p + 4);
        } else {
            a = make_float4(0.f,0.f,0.f,0.f); bq = make_float4(0.f,0.f,0.f,0.f);
        }
    };
    auto write_diag = [&](int mm, float4 a, float4 bq) {   // double-buffered
        float* dst = &sdiag[(mm & 1) * 4096 + dj*64 + dc];
        float v[8] = {a.x, a.y, a.z, a.w, bq.x, bq.y, bq.z, bq.w};
        #pragma unroll
        for (int e = 0; e < 8; ++e) dst[e] = (dj < dc + e) ? v[e] * LOG2E : 0.0f;
    };

    // ---- prologue ----
    const float x0 = x[0], x1 = x[1];
    float base = b[J0 + tid];
    #pragma unroll
    for (int r = 0; r < 8; ++r) base += cp[r * NN + J0 + tid];

    // pan[t-1][r]: W[row of current source, col of target t] for this wave's 8 rows
    float pan[7][8];
    #pragma unroll
    for (int t = 1; t <= 7; ++t)
        #pragma unroll
        for (int r = 0; r < 8; ++r)
            pan[t-1][r] = W[(size_t)(J0 + w*8 + r) * NN + (J0 + t*64 + l)];
    float racc[7];
    #pragma unroll
    for (int t = 0; t < 7; ++t) racc[t] = 0.0f;

    float4 dA[2], dB[2];
    load_diag(0, dA[0], dB[0]);
    load_diag(1, dA[1], dB[1]);
    write_diag(0, dA[0], dB[0]);
    LBAR();

    #pragma unroll
    for (int m = 0; m < 8; ++m) {
        if (w == m) {
            float rsum = 0.0f;
            if (m >= 1) {
                #pragma unroll
                for (int g = 0; g < 8; ++g) rsum += red[m][g][l];
            }
            float acc = (base + rsum) * LOG2E;
            float smine = 0.0f;
            const bool first = (k == 0) && (m == 0);
            #pragma unroll
            for (int j = 0; j < 64; ++j) {
                const float pre = bcastf(acc, j);
                float s;
                if (first && j == 0)      s = x0;
                else if (first && j == 1) s = x1;
                else                      s = sigm(pre);
                acc += sdiag[(m & 1) * 4096 + j*64 + l] * s;   // 0 for j>=l
                if (l == j) smine = s;
            }
            spub[m*64 + l] = smine;
            s_arr[J0 + m*64 + l] = smine;          // plain store; read next launches
            if (k == NSB - 1 && m == 7 && l == 63) out[0] = smine;
        }
        LBAR();                                    // spub visible to folds
        if (m < 7) {
            // fold source m into all future targets (this wave's 8 rows)
            #pragma unroll
            for (int r = 0; r < 8; ++r) {
                const float sv = spub[m*64 + w*8 + r];
                #pragma unroll
                for (int t = m + 1; t <= 7; ++t)
                    racc[t-1] += pan[t-1][r] * sv;
            }
            red[m+1][w][l] = racc[m];              // final for target m+1
            // reload panels for source m+1 (targets m+2..7); lands under next chain
            #pragma unroll
            for (int t = m + 2; t <= 7; ++t)
                #pragma unroll
                for (int r = 0; r < 8; ++r)
                    pan[t-1][r] = W[(size_t)(J0 + (m+1)*64 + w*8 + r) * NN
                                    + (J0 + t*64 + l)];
            // diag pipeline
            write_diag(m + 1, dA[(m+1) & 1], dB[(m+1) & 1]);
            if (m + 2 <= 7) load_diag(m + 2, dA[(m+2) & 1], dB[(m+2) & 1]);
            LBAR();                                // red + diag writes visible
        }
    }
}

// ---------- shared bulk body: 64 source rows (row-chunk rc) -> one target col ----------
// cp[rc][col] += sum ; single writer per (rc,col) per launch; launches are
// stream-serial => deterministic accumulation order.
__device__ void bulk_add(const float* __restrict__ W, float* wsf, float* ssh,
                         int rc, int src, int col) {
    const int tid = threadIdx.x;
    const float* s_arr = wsf + SARR_OFF;
    float* cp = wsf + CP_OFF;
    const int row0 = src * SBS + rc * 64;
    if (tid < 64) ssh[tid] = s_arr[row0 + tid];
    __syncthreads();
    const float* wp = W + (size_t)row0 * NN + col;
    float a0 = 0.f, a1 = 0.f, a2 = 0.f, a3 = 0.f;
    #pragma unroll
    for (int i = 0; i < 64; i += 4) {
        a0 += wp[(size_t)(i + 0) * NN] * ssh[i + 0];
        a1 += wp[(size_t)(i + 1) * NN] * ssh[i + 1];
        a2 += wp[(size_t)(i + 2) * NN] * ssh[i + 2];
        a3 += wp[(size_t)(i + 3) * NN] * ssh[i + 3];
    }
    cp[(size_t)rc * NN + col] += (a0 + a1) + (a2 + a3);
}

// solve(k) co-launched with far updates: source k-1 -> targets k+1..15
__global__ void __launch_bounds__(512, 1) solve_kernel(
    const float* __restrict__ W, const float* __restrict__ b,
    const float* __restrict__ x, float* wsf, float* __restrict__ out, int k)
{
    __shared__ float sdiag[2 * 4096];   // double-buffered diag, pre-scaled, 0 for j>=l
    __shared__ float spub[512];
    __shared__ float red[8][8][64];     // red[t][wave][lane], t=1..7
    __shared__ float ssh[64];
    if (blockIdx.x == 0) {
        solver_fn(W, b, x, wsf, sdiag, spub, red, out, k);
    } else {                             // grid > 1 only when k >= 1
        const int idx = blockIdx.x - 1;
        const int rc = idx & 7, cg = idx >> 3;
        bulk_add(W, wsf, ssh, rc, k - 1, (k + 1 + cg) * SBS + threadIdx.x);
    }
}

// near update: source k -> target k+1 (its own launch between solves)
__global__ void __launch_bounds__(512) near_kernel(
    const float* __restrict__ W, float* wsf, int k)
{
    __shared__ float ssh[64];
    bulk_add(W, wsf, ssh, blockIdx.x, k, (k + 1) * SBS + threadIdx.x);
}

extern "C" void kernel_launch(void* const* d_in, const int* in_sizes, int n_in,
                              void* d_out, int out_size, void* d_ws, size_t ws_size,
                              hipStream_t stream) {
    const float* x = (const float*)d_in[0];
    const float* W = (const float*)d_in[1];
    const float* b = (const float*)d_in[2];
    float* out = (float*)d_out;
    float* wsf = (float*)d_ws;

    init_ws<<<dim3(256), dim3(256), 0, stream>>>(wsf);
    for (int k = 0; k < NSB; ++k) {
        const int nb = 1 + ((k >= 1) ? 8 * (NSB - 1 - k) : 0);
        solve_kernel<<<dim3(nb), dim3(512), 0, stream>>>(W, b, x, wsf, out, k);
        if (k < NSB - 1)
            near_kernel<<<dim3(8), dim3(512), 0, stream>>>(W, wsf, k);
    }
}

// Round 13
// 500.688 us; speedup vs baseline: 1.8686x; 1.8686x over previous
//
#include <hip/hip_runtime.h>

#define NN 8192
#define SBS 256
#define NSB 32
#define LOG2E 1.44269504088896f

// ws floats (NO flags, NO atomics anywhere):
//   cp[8][NN] at [0, 65536): rows 0-3 = far-A/near accumulators, rows 4-7 = far-B
//   s_arr[NN] at [65536, 73728)
#define CP_OFF 0
#define SARR_OFF (8 * NN)

// panel id for source m -> target t within a block (0<=m<t<=3)
#define PID(m, t) ((m) == 0 ? (t) - 1 : ((m) == 1 ? 2 + (t) - 1 : 5))

__device__ __forceinline__ float bcastf(float v, int lane) {
    return __int_as_float(__builtin_amdgcn_readlane(__float_as_int(v), lane));
}
__device__ __forceinline__ float sigm(float prelog) {   // pre already in log2e units
    return __builtin_amdgcn_rcpf(1.0f + __builtin_amdgcn_exp2f(-prelog));
}
// barrier that does NOT drain vmcnt (keeps streamed prefetch loads in flight)
#define LBAR() do { asm volatile("s_waitcnt lgkmcnt(0)\ns_barrier" ::: "memory"); \
                    __builtin_amdgcn_sched_barrier(0); } while (0)

__global__ void init_ws(float* wsf) {
    int i = blockIdx.x * 256 + threadIdx.x;   // 256*256 = 65536 = 8*NN
    wsf[CP_OFF + i] = 0.0f;
}

// ---------- solver: 8 waves; chain waves 0..3, all 512 threads fold/stage ----------
__device__ void solver_fn(const float* __restrict__ W, const float* __restrict__ b,
                          const float* __restrict__ x, float* wsf,
                          float (*sdiag)[4096], float* spub, float* sacc,
                          float (*red4)[64], float* __restrict__ out, int k)
{
    const int tid = threadIdx.x;
    const int w = tid >> 6, l = tid & 63;
    const int dj = tid >> 3, dc = (tid & 7) * 8;      // diag staging role
    const int rgrp = tid >> 4, c4 = tid & 15;         // fold role: 2 rows x 4 cols
    const int J0 = k * SBS;
    const float* cp = wsf + CP_OFF;
    float* s_arr = wsf + SARR_OFF;

    auto load_diag = [&](int mm, float4& a, float4& bq) {
        if (dj < dc + 7) {   // chunks entirely at/below diagonal never used
            const float* p = &W[(size_t)(J0 + mm*64 + dj) * NN + (J0 + mm*64 + dc)];
            a  = *(const float4*)p;
            bq = *(const float4*)(p + 4);
        } else {
            a = make_float4(0.f,0.f,0.f,0.f); bq = make_float4(0.f,0.f,0.f,0.f);
        }
    };
    auto write_diag = [&](int mm, float4 a, float4 bq) {   // double-buffered
        float* dst = &sdiag[mm & 1][dj*64 + dc];
        float v[8] = {a.x, a.y, a.z, a.w, bq.x, bq.y, bq.z, bq.w};
        #pragma unroll
        for (int e = 0; e < 8; ++e) dst[e] = (dj < dc + e) ? v[e] * LOG2E : 0.0f;
    };

    // ---- prologue: base first (needed before LBAR), then diag, then panels ----
    const float x0 = x[0], x1 = x[1];
    if (tid < SBS) {
        float bs = b[J0 + tid];
        #pragma unroll
        for (int r = 0; r < 8; ++r) bs += cp[r * NN + J0 + tid];
        sacc[tid] = bs;
    }
    float4 dA[2], dB[2];
    load_diag(0, dA[0], dB[0]);
    load_diag(1, dA[1], dB[1]);

    // all 6 intra-block panels live in registers for the whole block (48 VGPRs)
    float4 pan[6][2];
    #pragma unroll
    for (int m = 0; m < 3; ++m)
        #pragma unroll
        for (int t = m + 1; t <= 3; ++t)
            #pragma unroll
            for (int rr = 0; rr < 2; ++rr)
                pan[PID(m,t)][rr] = *(const float4*)&W[
                    (size_t)(J0 + m*64 + rgrp*2 + rr) * NN + (J0 + t*64 + c4*4)];

    float4 racc[3];
    #pragma unroll
    for (int t = 0; t < 3; ++t) racc[t] = make_float4(0.f,0.f,0.f,0.f);
    write_diag(0, dA[0], dB[0]);
    LBAR();

    #pragma unroll
    for (int m = 0; m < 4; ++m) {
        if (w == m) {
            float rsum = 0.0f;
            if (m >= 1) {
                #pragma unroll
                for (int g = 0; g < 32; ++g) rsum += red4[g][l];
            }
            float acc = (sacc[m*64 + l] + rsum) * LOG2E;
            float smine = 0.0f;
            const bool first = (k == 0) && (m == 0);
            #pragma unroll
            for (int j = 0; j < 64; ++j) {
                const float pre = bcastf(acc, j);
                float s;
                if (first && j == 0)      s = x0;
                else if (first && j == 1) s = x1;
                else                      s = sigm(pre);
                acc += sdiag[m & 1][j*64 + l] * s;   // 0 for j>=l
                if (l == j) smine = s;
            }
            spub[m*64 + l] = smine;
            s_arr[J0 + m*64 + l] = smine;            // plain store; later launches read
            if (k == NSB - 1 && m == 3 && l == 63) out[0] = smine;
        }
        LBAR();                                      // spub visible to folds
        if (m < 3) {
            // fold source m into all pending targets (float4, register panels)
            const float sv0 = spub[m*64 + rgrp*2 + 0];
            const float sv1 = spub[m*64 + rgrp*2 + 1];
            #pragma unroll
            for (int t = m + 1; t <= 3; ++t) {
                const int pid = PID(m, t);
                float4& ra = racc[t-1];
                ra.x += pan[pid][0].x * sv0; ra.x += pan[pid][1].x * sv1;
                ra.y += pan[pid][0].y * sv0; ra.y += pan[pid][1].y * sv1;
                ra.z += pan[pid][0].z * sv0; ra.z += pan[pid][1].z * sv1;
                ra.w += pan[pid][0].w * sv0; ra.w += pan[pid][1].w * sv1;
            }
            *(float4*)&red4[rgrp][c4*4] = racc[m];   // target m+1 now final
            // diag staging pipeline
            write_diag(m + 1, dA[(m+1) & 1], dB[(m+1) & 1]);
            if (m + 2 <= 3) load_diag(m + 2, dA[(m+2) & 1], dB[(m+2) & 1]);
            LBAR();                                  // red4 + diag writes visible
        }
    }
}

// ---------- 64-row x ncols dot-add into a cp row (single writer per launch) ----------
__device__ void bulk_add(const float* __restrict__ W, float* wsf, float* ssh,
                         int cprow, int row0, int colbase, int ncols) {
    const int tid = threadIdx.x;
    const float* s_arr = wsf + SARR_OFF;
    float* cp = wsf + CP_OFF;
    if (tid < 64) ssh[tid] = s_arr[row0 + tid];
    __syncthreads();
    const int col = colbase + tid;
    if (tid < ncols && col < NN) {
        const float* wp = W + (size_t)row0 * NN + col;
        float a0 = 0.f, a1 = 0.f, a2 = 0.f, a3 = 0.f;
        #pragma unroll
        for (int i = 0; i < 64; i += 4) {
            a0 += wp[(size_t)(i + 0) * NN] * ssh[i + 0];
            a1 += wp[(size_t)(i + 1) * NN] * ssh[i + 1];
            a2 += wp[(size_t)(i + 2) * NN] * ssh[i + 2];
            a3 += wp[(size_t)(i + 3) * NN] * ssh[i + 3];
        }
        cp[(size_t)cprow * NN + col] += (a0 + a1) + (a2 + a3);
    }
}

// solve(k): solver WG + co-launched far workers (all read only data from launches < k)
//   far-B (bids 1..4):  source block k-1 -> target block k+1 cols, cp rows 4..7
//   far-A (bids 5.. ):  source block k-2 -> cols >= (k+1)*SBS, cp rows 0..3
__global__ void __launch_bounds__(512, 1) solve_kernel(
    const float* __restrict__ W, const float* __restrict__ b,
    const float* __restrict__ x, float* wsf, float* __restrict__ out, int k)
{
    __shared__ float sdiag[2][4096];
    __shared__ float spub[SBS];
    __shared__ float sacc[SBS];
    __shared__ float red4[32][64];
    __shared__ float ssh[64];
    const int bid = blockIdx.x;
    if (bid == 0) {
        solver_fn(W, b, x, wsf, sdiag, spub, sacc, red4, out, k);
    } else if (bid <= 4) {
        const int rc = bid - 1;
        bulk_add(W, wsf, ssh, 4 + rc, (k-1)*SBS + rc*64, (k+1)*SBS, 256);
    } else {
        const int idx = bid - 5;
        const int rc = idx & 3, span = idx >> 2;
        bulk_add(W, wsf, ssh, rc, (k-2)*SBS + rc*64, (k+1)*SBS + span*512, 512);
    }
}

// near(k): source block k -> target block k+1 (own node between solves; dist-1)
__global__ void __launch_bounds__(256) near_kernel(const float* __restrict__ W,
                                                   float* wsf, int k) {
    __shared__ float ssh[64];
    bulk_add(W, wsf, ssh, blockIdx.x, k*SBS + blockIdx.x*64, (k+1)*SBS, 256);
}

extern "C" void kernel_launch(void* const* d_in, const int* in_sizes, int n_in,
                              void* d_out, int out_size, void* d_ws, size_t ws_size,
                              hipStream_t stream) {
    const float* x = (const float*)d_in[0];
    const float* W = (const float*)d_in[1];
    const float* b = (const float*)d_in[2];
    float* out = (float*)d_out;
    float* wsf = (float*)d_ws;

    init_ws<<<dim3(256), dim3(256), 0, stream>>>(wsf);
    for (int k = 0; k < NSB; ++k) {
        int nb = 1;
        if (k >= 1 && k <= NSB - 2) nb += 4;                      // far-B
        if (k >= 2 && k <= NSB - 2) nb += 4 * ((NSB - k) / 2);    // far-A spans
        solve_kernel<<<dim3(nb), dim3(512), 0, stream>>>(W, b, x, wsf, out, k);
        if (k < NSB - 1)
            near_kernel<<<dim3(4), dim3(256), 0, stream>>>(W, wsf, k);
    }
}